// Round 1
// baseline (352.864 us; speedup 1.0000x reference)
//
#include <hip/hip_runtime.h>
#include <math.h>

// Problem constants (from reference)
#define NN 100000          // nodes
#define LF 48              // features per node
#define NE 1600000         // edges
#define EDIMS 17           // edge_attr dim
#define MASKW 3125         // NN/32 bitmask words
#define CAP_E 16384        // per-level edge-list capacity (expected ~5k max level)
#define MAXLOC 12288       // active-node capacity (expected ~4.9k)

static_assert(NN == MASKW * 32, "mask width");
static_assert((CAP_E & (CAP_E - 1)) == 0, "CAP_E pow2");

__device__ __forceinline__ float gelu_f(float x) {
    // jax.nn.gelu(approximate=False) = x * 0.5 * (1 + erf(x/sqrt(2)))
    return 0.5f * x * (1.0f + erff(x * 0.7071067811865475f));
}
__device__ __forceinline__ float sigm_f(float x) {
    return 1.0f / (1.0f + expf(-x));
}

__global__ void seed_kernel(unsigned* __restrict__ M3) {
    if (threadIdx.x == 0 && blockIdx.x == 0) M3[0] = 1u;   // node 0 bit
}

// For each edge with dst in Min: append edge to list, OR src into Mout.
// Mout starts as a copy of Min, so Mout = Min ∪ src(selected edges).
__global__ void expand_kernel(const int* __restrict__ src, const int* __restrict__ dst,
                              const unsigned* __restrict__ Min, unsigned* __restrict__ Mout,
                              int4* __restrict__ list, int* __restrict__ counter)
{
    int e = blockIdx.x * 256 + threadIdx.x;
    if (e >= NE) return;
    int d = dst[e];
    if (Min[d >> 5] & (1u << (d & 31))) {
        int s = src[e];
        int idx = atomicAdd(counter, 1);
        if (idx < CAP_E) list[idx] = make_int4(s, d, e, 0);
        atomicOr(&Mout[s >> 5], 1u << (s & 31));
    }
}

__global__ void compact_kernel(const unsigned* __restrict__ M0, int* __restrict__ n2l,
                               int* __restrict__ l2n, int* __restrict__ nloc)
{
    int w = blockIdx.x * 256 + threadIdx.x;
    if (w >= MASKW) return;
    unsigned bits = M0[w];
    while (bits) {
        int b = __ffs(bits) - 1;
        bits &= bits - 1;
        int node = w * 32 + b;
        int loc = atomicAdd(nloc, 1);
        if (loc < MAXLOC) { n2l[node] = loc; l2n[loc] = node; }
    }
}

// x0 = nodes*valid, v0 = valid, meanv0
__global__ void init_kernel(const int* __restrict__ nloc_p, const int* __restrict__ l2n,
                            const float* __restrict__ nodes, const float* __restrict__ valid,
                            float* __restrict__ X0, float* __restrict__ V0, float* __restrict__ MV0)
{
    int loc = blockIdx.x * 256 + threadIdx.x;
    int nl = *nloc_p; if (nl > MAXLOC) nl = MAXLOC;
    if (loc >= nl) return;
    int node = l2n[loc];
    float sum = 0.f;
    #pragma unroll 4
    for (int l = 0; l < LF; ++l) {
        float v = valid[node * LF + l];
        float x = nodes[node * LF + l] * v;
        X0[loc * LF + l] = x;
        V0[loc * LF + l] = v;
        sum += v;
    }
    MV0[loc] = sum * (1.0f / 48.0f);
}

// One 64-thread block per listed edge: compute loop-invariant scalar
//   w0 = gelu(relu(gelu(ea@W1+b1)@W2+b2)@Wg+bg)@Ww + bw
// and remap (src,dst) node ids -> local indices. Result packed back into list.
__global__ void w0_kernel(int4* __restrict__ lists, const int* __restrict__ counts,
                          const int* __restrict__ n2l, const float* __restrict__ ea_g,
                          const float* __restrict__ W1, const float* __restrict__ b1,
                          const float* __restrict__ W2, const float* __restrict__ b2,
                          const float* __restrict__ Wg, const float* __restrict__ bg,
                          const float* __restrict__ Ww, const float* __restrict__ bw)
{
    int t = blockIdx.x >> 14;            // / CAP_E
    int i = blockIdx.x & (CAP_E - 1);
    int c = counts[t]; if (c > CAP_E) c = CAP_E;
    if (i >= c) return;
    int4 ent = lists[t * CAP_E + i];
    __shared__ float sh[64];
    __shared__ float eas[EDIMS];
    int lane = threadIdx.x;
    if (lane < EDIMS) eas[lane] = ea_g[(long)ent.z * EDIMS + lane];
    __syncthreads();
    float h1 = 0.f;
    if (lane < 48) {
        float acc = b1[lane];
        #pragma unroll
        for (int k = 0; k < EDIMS; ++k) acc += eas[k] * W1[k * 48 + lane];
        h1 = gelu_f(acc);
    }
    sh[lane] = h1;
    __syncthreads();
    float h2 = 0.f;
    if (lane < 48) {
        float acc = b2[lane];
        #pragma unroll 8
        for (int k = 0; k < 48; ++k) acc += sh[k] * W2[k * 48 + lane];
        h2 = fmaxf(acc, 0.f);
    }
    __syncthreads();
    sh[lane] = h2;
    __syncthreads();
    float part = 0.f;
    if (lane < 48) {
        float acc = bg[lane];
        #pragma unroll 8
        for (int k = 0; k < 48; ++k) acc += sh[k] * Wg[k * 48 + lane];
        part = gelu_f(acc) * Ww[lane];
    }
    #pragma unroll
    for (int offd = 32; offd > 0; offd >>= 1) part += __shfl_down(part, offd, 64);
    if (lane == 0) {
        float w0 = part + bw[0];
        int sl = n2l[ent.x]; if ((unsigned)sl >= MAXLOC) sl = 0;
        int dl = n2l[ent.y]; if ((unsigned)dl >= MAXLOC) dl = 0;
        lists[t * CAP_E + i] = make_int4(sl, dl, ent.z, __float_as_int(w0));
    }
}

// agg[dst] += sigmoid(meanv[src]*w0) * x_prev[src]   (48 lanes per edge)
__global__ void edge_agg_kernel(const int4* __restrict__ list, const int* __restrict__ count_p,
                                const float* __restrict__ Xprev, const float* __restrict__ MVprev,
                                float* __restrict__ agg)
{
    int gid = blockIdx.x * 256 + threadIdx.x;
    int i = gid >> 6, lane = gid & 63;
    int c = *count_p; if (c > CAP_E) c = CAP_E;
    if (i >= c || lane >= 48) return;
    int4 ent = list[i];
    if ((unsigned)ent.x >= MAXLOC || (unsigned)ent.y >= MAXLOC) return;
    float s = sigm_f(MVprev[ent.x] * __int_as_float(ent.w));
    atomicAdd(&agg[ent.y * 48 + lane], s * Xprev[ent.x * 48 + lane]);
}

// Per-node update for nodes in mask Mt:
// m = sigmoid(nh*Wf0 + x*Wf1 + nv*Wf2 + bf); x' = (1-m)x + nv*m*nh;
// v' = (orig != x') | (v>0); v'[:,0]=0; meanv' = mean(v')
__global__ void node_update_kernel(const int* __restrict__ nloc_p, const int* __restrict__ l2n,
                                   const unsigned* __restrict__ Mt,
                                   const float* __restrict__ agg, const float* __restrict__ Xprev,
                                   const float* __restrict__ Vprev, const float* __restrict__ Xorig,
                                   float* __restrict__ Xcur, float* __restrict__ Vcur,
                                   float* __restrict__ MVcur,
                                   const float* __restrict__ Wf, const float* __restrict__ bf)
{
    int loc = blockIdx.x * 256 + threadIdx.x;
    int nl = *nloc_p; if (nl > MAXLOC) nl = MAXLOC;
    if (loc >= nl) return;
    int node = l2n[loc];
    if (!(Mt[node >> 5] & (1u << (node & 31)))) return;
    float wf0 = Wf[0], wf1 = Wf[1], wf2 = Wf[2], bfs = bf[0];
    float vsum = 0.f;
    #pragma unroll 4
    for (int l = 0; l < LF; ++l) {
        float nh = agg[loc * LF + l];
        float xo = Xprev[loc * LF + l];
        float vp = Vprev[loc * LF + l];
        float nv = 1.0f - vp;
        float m = sigm_f(nh * wf0 + xo * wf1 + nv * wf2 + bfs);
        float xn = (1.0f - m) * xo + nv * m * nh;
        float vn = ((Xorig[loc * LF + l] != xn) || (vp > 0.f)) ? 1.0f : 0.0f;
        if (l == 0) vn = 0.0f;
        Xcur[loc * LF + l] = xn;
        Vcur[loc * LF + l] = vn;
        vsum += vn;
    }
    MVcur[loc] = vsum * (1.0f / 48.0f);
}

__global__ void output_kernel(const int* __restrict__ n2l, const float* __restrict__ Xf,
                              float* __restrict__ out)
{
    int l = threadIdx.x;
    if (l < 48) out[l] = Xf[n2l[0] * 48 + l];
}

extern "C" void kernel_launch(void* const* d_in, const int* in_sizes, int n_in,
                              void* d_out, int out_size, void* d_ws, size_t ws_size,
                              hipStream_t stream)
{
    const float* nodes = (const float*)d_in[0];
    const int*   eidx  = (const int*)d_in[1];     // (2,E) int32
    const float* eattr = (const float*)d_in[2];
    const float* valid = (const float*)d_in[3];
    // d_in[4]=r, d_in[5]=fx unused by reference
    const float* W1 = (const float*)d_in[6];
    const float* b1 = (const float*)d_in[7];
    const float* W2 = (const float*)d_in[8];
    const float* b2 = (const float*)d_in[9];
    const float* Wg = (const float*)d_in[10];
    const float* bg = (const float*)d_in[11];
    const float* Ww = (const float*)d_in[12];
    const float* bw = (const float*)d_in[13];
    const float* Wf = (const float*)d_in[14];
    const float* bf = (const float*)d_in[15];
    const int* src = eidx;
    const int* dst = eidx + NE;

    char* ws = (char*)d_ws;
    size_t off = 0;
    auto alloc = [&](size_t bytes) -> char* {
        char* p = ws + off;
        off += (bytes + 255) & ~(size_t)255;
        return p;
    };
    int*      counters = (int*)alloc(64);                   // [0]=|E3| [1]=|E2| [2]=|E1| [3]=nloc
    unsigned* M3 = (unsigned*)alloc(MASKW * 4);             // S3 = {0}
    unsigned* M2 = (unsigned*)alloc(MASKW * 4);             // S2 = S3 ∪ src(E3)
    unsigned* M1 = (unsigned*)alloc(MASKW * 4);             // S1 = S2 ∪ src(E2)
    unsigned* M0 = (unsigned*)alloc(MASKW * 4);             // S0 = S1 ∪ src(E1) (active set)
    int*      n2l = (int*)alloc((size_t)NN * 4);            // only active entries ever read
    int*      l2n = (int*)alloc((size_t)MAXLOC * 4);
    int4*     lists = (int4*)alloc((size_t)3 * CAP_E * 16); // slot0=E3, slot1=E2, slot2=E1
    float*    X0 = (float*)alloc((size_t)MAXLOC * LF * 4);  // original (and x_prev for iter 1)
    float*    XA = (float*)alloc((size_t)MAXLOC * LF * 4);
    float*    XB = (float*)alloc((size_t)MAXLOC * LF * 4);
    float*    VA = (float*)alloc((size_t)MAXLOC * LF * 4);
    float*    VB = (float*)alloc((size_t)MAXLOC * LF * 4);
    float*    MVA = (float*)alloc((size_t)MAXLOC * 4);
    float*    MVB = (float*)alloc((size_t)MAXLOC * 4);
    float*    agg = (float*)alloc((size_t)MAXLOC * LF * 4);
    if (off > ws_size) return;   // ~15.5 MB needed; fail loudly rather than corrupt

    hipMemsetAsync(counters, 0, 64, stream);
    hipMemsetAsync(M3, 0, MASKW * 4, stream);
    hipMemsetAsync(M2, 0, MASKW * 4, stream);
    hipMemsetAsync(M1, 0, MASKW * 4, stream);
    hipMemsetAsync(M0, 0, MASKW * 4, stream);
    seed_kernel<<<1, 64, 0, stream>>>(M3);

    // Backward BFS: exact dst-sets per iteration (snapshot semantics via separate in/out masks)
    hipMemcpyAsync(M2, M3, MASKW * 4, hipMemcpyDeviceToDevice, stream);
    expand_kernel<<<NE / 256, 256, 0, stream>>>(src, dst, M3, M2, lists + 0 * CAP_E, counters + 0);
    hipMemcpyAsync(M1, M2, MASKW * 4, hipMemcpyDeviceToDevice, stream);
    expand_kernel<<<NE / 256, 256, 0, stream>>>(src, dst, M2, M1, lists + 1 * CAP_E, counters + 1);
    hipMemcpyAsync(M0, M1, MASKW * 4, hipMemcpyDeviceToDevice, stream);
    expand_kernel<<<NE / 256, 256, 0, stream>>>(src, dst, M1, M0, lists + 2 * CAP_E, counters + 2);

    compact_kernel<<<(MASKW + 255) / 256, 256, 0, stream>>>(M0, n2l, l2n, counters + 3);
    init_kernel<<<MAXLOC / 256, 256, 0, stream>>>(counters + 3, l2n, nodes, valid, X0, VA, MVA);
    w0_kernel<<<3 * CAP_E, 64, 0, stream>>>(lists, counters, n2l, eattr,
                                            W1, b1, W2, b2, Wg, bg, Ww, bw);

    const size_t aggBytes = (size_t)MAXLOC * LF * 4;
    // iter 1: prev = X0/VA/MVA -> cur = XA/VB/MVB, edges E1 (slot2), nodes M1
    hipMemsetAsync(agg, 0, aggBytes, stream);
    edge_agg_kernel<<<CAP_E * 64 / 256, 256, 0, stream>>>(lists + 2 * CAP_E, counters + 2, X0, MVA, agg);
    node_update_kernel<<<MAXLOC / 256, 256, 0, stream>>>(counters + 3, l2n, M1, agg, X0, VA, X0,
                                                         XA, VB, MVB, Wf, bf);
    // iter 2: XA/VB/MVB -> XB/VA/MVA, edges E2 (slot1), nodes M2
    hipMemsetAsync(agg, 0, aggBytes, stream);
    edge_agg_kernel<<<CAP_E * 64 / 256, 256, 0, stream>>>(lists + 1 * CAP_E, counters + 1, XA, MVB, agg);
    node_update_kernel<<<MAXLOC / 256, 256, 0, stream>>>(counters + 3, l2n, M2, agg, XA, VB, X0,
                                                         XB, VA, MVA, Wf, bf);
    // iter 3: XB/VA/MVA -> XA/VB/MVB, edges E3 (slot0), nodes M3 (= node 0 only)
    hipMemsetAsync(agg, 0, aggBytes, stream);
    edge_agg_kernel<<<CAP_E * 64 / 256, 256, 0, stream>>>(lists + 0 * CAP_E, counters + 0, XB, MVA, agg);
    node_update_kernel<<<MAXLOC / 256, 256, 0, stream>>>(counters + 3, l2n, M3, agg, XB, VA, X0,
                                                         XA, VB, MVB, Wf, bf);

    output_kernel<<<1, 64, 0, stream>>>(n2l, XA, (float*)d_out);
}